// Round 8
// baseline (1134.549 us; speedup 1.0000x reference)
//
#include <hip/hip_runtime.h>
#include <cstdint>
#include <cstddef>

typedef _Float16 f16;
typedef _Float16 f16x4 __attribute__((ext_vector_type(4)));
typedef _Float16 f16x8 __attribute__((ext_vector_type(8)));
typedef float f32x4 __attribute__((ext_vector_type(4)));

// ---------------------------------------------------------------------------
// Weight prep via LDS-bounce transpose. Tile 32 o x 32 i per block.
// Wt[o][i*9+0] = sb[i,o]; Wt[o][i*9+1+g] = coef[i,o,g]*ss[i,o].
// ---------------------------------------------------------------------------
__global__ __launch_bounds__(256) void kan_prep2(
    const float* __restrict__ coef, const float* __restrict__ sb,
    const float* __restrict__ ss, f16* __restrict__ Wt,
    int out, int K9)
{
  __shared__ float s_sb[32][32];   // [i][o]
  __shared__ float s_ss[32][32];
  __shared__ f16 s_w[32][288];     // [o][i*9+t]
  const int t  = threadIdx.x;
  const int o0 = blockIdx.x * 32, i0 = blockIdx.y * 32;

  {
    int il = t >> 3, oc = (t & 7) * 4;
    float4 vb = *(const float4*)(sb + (size_t)(i0 + il) * out + o0 + oc);
    float4 vs = *(const float4*)(ss + (size_t)(i0 + il) * out + o0 + oc);
    s_sb[il][oc + 0] = vb.x; s_sb[il][oc + 1] = vb.y;
    s_sb[il][oc + 2] = vb.z; s_sb[il][oc + 3] = vb.w;
    s_ss[il][oc + 0] = vs.x; s_ss[il][oc + 1] = vs.y;
    s_ss[il][oc + 2] = vs.z; s_ss[il][oc + 3] = vs.w;
  }
  __syncthreads();

#pragma unroll
  for (int j = 0; j < 8; ++j) {
    int f  = j * 256 + t;
    int il = f >> 6, c = f & 63;
    int ol = c >> 1, gh = (c & 1) * 4;
    float4 v = *(const float4*)(coef + ((size_t)(i0 + il) * out + (o0 + ol)) * 8 + gh);
    float ssv = s_ss[il][ol];
    f16* dst = &s_w[ol][il * 9 + 1 + gh];
    dst[0] = (f16)(v.x * ssv); dst[1] = (f16)(v.y * ssv);
    dst[2] = (f16)(v.z * ssv); dst[3] = (f16)(v.w * ssv);
  }
#pragma unroll
  for (int j = 0; j < 4; ++j) {
    int e = j * 256 + t; int il = e >> 5, ol = e & 31;
    s_w[ol][il * 9] = (f16)s_sb[il][ol];
  }
  __syncthreads();

  {
    int o = t >> 3, part = t & 7;
    f16* dst = Wt + (size_t)(o0 + o) * K9 + (size_t)i0 * 9 + part * 36;
    const f16* src = &s_w[o][part * 36];
#pragma unroll
    for (int q = 0; q < 9; ++q)
      *(f16x4*)(dst + q * 4) = *(const f16x4*)(src + q * 4);
  }
}

// ---------------------------------------------------------------------------
// Features: per x -> [silu(x), B3_0(x)..B3_7(x)] fp16, row-major F[b][i*9+t].
// Uniform pykan grid hardcoded: t_j = (j-3)*0.4 - 1.
// ---------------------------------------------------------------------------
__global__ __launch_bounds__(256) void kan_feat(
    const float* __restrict__ X, f16* __restrict__ F,
    int shift, int K9, int iBase)
{
  int idx = blockIdx.x * 256 + threadIdx.x;
  int b  = idx >> shift;
  int ii = idx & ((1 << shift) - 1);
  float x = X[idx];

  float sig  = 1.0f / (1.0f + __expf(-x));
  float silu = x * sig;

  float t[12];
#pragma unroll
  for (int j = 0; j < 12; ++j) t[j] = (float)(j - 3) * 0.4f - 1.0f;
  float b0[11];
#pragma unroll
  for (int j = 0; j < 11; ++j)
    b0[j] = (x >= t[j] && x < t[j + 1]) ? 1.0f : 0.0f;
  float b1[10];
#pragma unroll
  for (int j = 0; j < 10; ++j)
    b1[j] = (x - t[j]) * 2.5f * b0[j] + (t[j + 2] - x) * 2.5f * b0[j + 1];
  float b2[9];
#pragma unroll
  for (int j = 0; j < 9; ++j)
    b2[j] = (x - t[j]) * 1.25f * b1[j] + (t[j + 3] - x) * 1.25f * b1[j + 1];
  float b3[8];
#pragma unroll
  for (int j = 0; j < 8; ++j)
    b3[j] = (x - t[j]) * (1.0f / 1.2f) * b2[j] +
            (t[j + 4] - x) * (1.0f / 1.2f) * b2[j + 1];

  f16* o = F + (size_t)b * K9 + (size_t)(iBase + ii) * 9;
  o[0] = (f16)silu;
#pragma unroll
  for (int g = 0; g < 8; ++g) o[1 + g] = (f16)b3[g];
}

// ---------------------------------------------------------------------------
// GEMM: C[M,N] += A[M,K] * Bt[N,K]^T, fp16 in / fp32 out.
// BARRIER-FREE DIRECT-GATHER (R8): no LDS, no __syncthreads, no gl2lds.
// Each wave gathers its own MFMA fragments straight from global memory:
// af[mi] is ONE global_load_dwordx4 with per-lane address (row=l16)*K+quad*8
// — 16 fully-consumed 64B segments per instruction, same line efficiency as
// a contiguous 1KB load. Compiler software-pipelines plain loads across the
// unrolled K-loop with fine-grained vmcnt (its verified strength, m97 asm).
// R7 post-mortem: with depth-3 prefetch loads had ~6000cy to land yet waves
// were 58% idle -> the barrier convoy itself (4 waves x 2 phase-locked
// blocks resyncing every ~310cy) was the residual limiter. Removed.
// Duplicate reads between wave pairs hit L1 (16KB unique/step << 32KB L1);
// L2 unique demand ~52 B/cy/CU, under the ~60 ceiling.
// Block 128x128, 4 waves 2x2, wave 64x64, acc[4][4].
// ---------------------------------------------------------------------------
template <int SPLITK>
__global__ __launch_bounds__(256, 2) void kan_gemm(
    const f16* __restrict__ A, const f16* __restrict__ Bt,
    float* __restrict__ C, int N, int K)
{
  const int tid   = threadIdx.x;
  const int lane  = tid & 63;
  const int w     = tid >> 6;
  const int waveM = w >> 1, waveN = w & 1;
  const int l16   = lane & 15, quad = lane >> 4;
  const size_t mBase = (size_t)blockIdx.y * 128;
  const size_t nBase = (size_t)blockIdx.x * 128;
  const int kChunk = K / SPLITK;
  const int k0     = blockIdx.z * kChunk;
  const int kSteps = kChunk >> 5;

  // per-lane fragment gather pointers (advance by 32 f16 per K-step)
  const f16* pA[4]; const f16* pB[4];
#pragma unroll
  for (int mi = 0; mi < 4; ++mi)
    pA[mi] = A + (mBase + waveM * 64 + mi * 16 + l16) * (size_t)K + k0 + quad * 8;
#pragma unroll
  for (int ni = 0; ni < 4; ++ni)
    pB[ni] = Bt + (nBase + waveN * 64 + ni * 16 + l16) * (size_t)K + k0 + quad * 8;

  f32x4 acc[4][4] = {};

#pragma unroll 2
  for (int s = 0; s < kSteps; ++s) {
    f16x8 af[4], bf[4];
#pragma unroll
    for (int mi = 0; mi < 4; ++mi) {
      af[mi] = *(const f16x8*)pA[mi];
      pA[mi] += 32;
    }
#pragma unroll
    for (int ni = 0; ni < 4; ++ni) {
      bf[ni] = *(const f16x8*)pB[ni];
      pB[ni] += 32;
    }
#pragma unroll
    for (int mi = 0; mi < 4; ++mi)
#pragma unroll
      for (int ni = 0; ni < 4; ++ni)
        acc[mi][ni] = __builtin_amdgcn_mfma_f32_16x16x32_f16(
            af[mi], bf[ni], acc[mi][ni], 0, 0, 0);
  }

#pragma unroll
  for (int mi = 0; mi < 4; ++mi) {
    size_t row = mBase + waveM * 64 + mi * 16 + quad * 4;
#pragma unroll
    for (int ni = 0; ni < 4; ++ni) {
      size_t col = nBase + waveN * 64 + ni * 16 + l16;
#pragma unroll
      for (int r = 0; r < 4; ++r)
        unsafeAtomicAdd(C + (row + r) * N + col, acc[mi][ni][r]);
    }
  }
}

// ---------------------------------------------------------------------------
// Orchestration. WS: Wt (18.9MB) | F (75.5MB) | actA | actB (16.8MB each).
// All GEMM grids = 512 blocks -> 2 resident/CU (VGPR<=256 via launch_bounds).
// ---------------------------------------------------------------------------
extern "C" void kernel_launch(void* const* d_in, const int* in_sizes, int n_in,
                              void* d_out, int out_size, void* d_ws, size_t ws_size,
                              hipStream_t stream)
{
  const float* y = (const float*)d_in[0];
  const float* u = (const float*)d_in[1];
  const float* coef[4]; const float* sb[4]; const float* ss[4];
  for (int l = 0; l < 4; ++l) {
    coef[l] = (const float*)d_in[2 + 4 * l];
    sb[l]   = (const float*)d_in[3 + 4 * l];
    ss[l]   = (const float*)d_in[4 + 4 * l];
  }
  char* ws = (char*)d_ws;
  f16*   Wt   = (f16*)(ws);
  f16*   F    = (f16*)(ws + 18874368);                        // 9216*1024*2
  float* actA = (float*)(ws + 18874368 + 75497472);           // + 4096*9216*2
  float* actB = (float*)(ws + 18874368 + 75497472 + 16777216);
  float* out  = (float*)d_out;
  const size_t actBytes = (size_t)4096 * 1024 * 4;

  // Layer 0: in=512 (concat y|u), out=1024, K=4608. splitK=2 (kSteps 72).
  kan_prep2<<<dim3(32, 16), 256, 0, stream>>>(coef[0], sb[0], ss[0], Wt, 1024, 4608);
  kan_feat<<<4096 * 256 / 256, 256, 0, stream>>>(y, F, 8, 4608, 0);
  kan_feat<<<4096 * 256 / 256, 256, 0, stream>>>(u, F, 8, 4608, 256);
  hipMemsetAsync(actA, 0, actBytes, stream);
  kan_gemm<2><<<dim3(8, 32, 2), 256, 0, stream>>>(F, Wt, actA, 1024, 4608);

  // Layer 1: in=1024, out=1024, K=9216. splitK=2 (kSteps 144).
  kan_prep2<<<dim3(32, 32), 256, 0, stream>>>(coef[1], sb[1], ss[1], Wt, 1024, 9216);
  kan_feat<<<4096 * 1024 / 256, 256, 0, stream>>>(actA, F, 10, 9216, 0);
  hipMemsetAsync(actB, 0, actBytes, stream);
  kan_gemm<2><<<dim3(8, 32, 2), 256, 0, stream>>>(F, Wt, actB, 1024, 9216);

  // Layer 2: in=1024, out=1024, K=9216. splitK=2.
  kan_prep2<<<dim3(32, 32), 256, 0, stream>>>(coef[2], sb[2], ss[2], Wt, 1024, 9216);
  kan_feat<<<4096 * 1024 / 256, 256, 0, stream>>>(actB, F, 10, 9216, 0);
  hipMemsetAsync(actA, 0, actBytes, stream);
  kan_gemm<2><<<dim3(8, 32, 2), 256, 0, stream>>>(F, Wt, actA, 1024, 9216);

  // Layer 3: in=1024, out=256, K=9216. splitK=8 -> 512 blocks (kSteps 36).
  kan_prep2<<<dim3(8, 32), 256, 0, stream>>>(coef[3], sb[3], ss[3], Wt, 256, 9216);
  kan_feat<<<4096 * 1024 / 256, 256, 0, stream>>>(actA, F, 10, 9216, 0);
  hipMemsetAsync(d_out, 0, (size_t)out_size * sizeof(float), stream);
  kan_gemm<8><<<dim3(2, 32, 8), 256, 0, stream>>>(F, Wt, out, 256, 9216);
}